// Round 13
// baseline (130.757 us; speedup 1.0000x reference)
//
#include <hip/hip_runtime.h>

typedef unsigned short u16;
typedef unsigned int   u32;

typedef __attribute__((ext_vector_type(4))) float f32x4;
typedef __attribute__((ext_vector_type(8))) short bf16x8;

#define HWDIM 4096
#define CDIM  256

__device__ __forceinline__ float bf2f(u16 u) { return __uint_as_float(((u32)u) << 16); }
__device__ __forceinline__ u16 f2bf(float f) {
    u32 u = __float_as_uint(f);
    u32 r = (u + 0x7fffu + ((u >> 16) & 1u)) >> 16;   // RNE
    return (u16)r;
}
__device__ __forceinline__ void unpack8(uint4 r, float* f) {
    f[0] = __uint_as_float(r.x << 16); f[1] = __uint_as_float(r.x & 0xffff0000u);
    f[2] = __uint_as_float(r.y << 16); f[3] = __uint_as_float(r.y & 0xffff0000u);
    f[4] = __uint_as_float(r.z << 16); f[5] = __uint_as_float(r.z & 0xffff0000u);
    f[6] = __uint_as_float(r.w << 16); f[7] = __uint_as_float(r.w & 0xffff0000u);
}

// async global->LDS, 16 B per lane; lds dest = wave-uniform base + lane*16 (m104/m108)
#define GLL16(g, l) \
    __builtin_amdgcn_global_load_lds((const __attribute__((address_space(1))) u32*)(g), \
                                     (__attribute__((address_space(3))) u32*)(l), 16, 0, 0)

// ---------------- diagnostic fill (only if ws_size too small; ws measured 256 MiB) ----
__global__ __launch_bounds__(256) void fill_kernel(float* __restrict__ out, int n) {
    int i = blockIdx.x * 256 + threadIdx.x;
    if (i < n) out[i] = 1.0f;
}

// ---------------- kernel 0: fused prep = ln_stats (bx<1024) + weight/bias conv -------
__global__ __launch_bounds__(256) void prep_kernel(const float* __restrict__ x,
                                                   const float* __restrict__ Wq,
                                                   const float* __restrict__ Wk,
                                                   const float* __restrict__ Wv,
                                                   const float* __restrict__ Wo,
                                                   const float* __restrict__ bq,
                                                   const float* __restrict__ bk,
                                                   const float* __restrict__ bv,
                                                   u16* __restrict__ Wqkv,
                                                   u16* __restrict__ Woc,
                                                   float* __restrict__ biasStack,
                                                   float2* __restrict__ stats) {
    int bx = blockIdx.x;
    int t = threadIdx.x;
    if (bx < 1024) {
        const float* px = x + (size_t)bx * HWDIM;
        float sum = 0.f, ss = 0.f;
#pragma unroll
        for (int it = 0; it < 4; ++it) {
            float4 v = *(const float4*)(px + (t + it * 256) * 4);
            sum += v.x + v.y + v.z + v.w;
            ss  += v.x * v.x + v.y * v.y + v.z * v.z + v.w * v.w;
        }
#pragma unroll
        for (int o = 32; o; o >>= 1) { sum += __shfl_xor(sum, o); ss += __shfl_xor(ss, o); }
        __shared__ float s1[4], s2[4];
        int wid = t >> 6, lane = t & 63;
        if (lane == 0) { s1[wid] = sum; s2[wid] = ss; }
        __syncthreads();
        if (t == 0) {
            float S = s1[0] + s1[1] + s1[2] + s1[3];
            float Q = s2[0] + s2[1] + s2[2] + s2[3];
            float mu  = S * (1.f / HWDIM);
            float var = Q * (1.f / HWDIM) - mu * mu;
            stats[bx] = make_float2(mu, rsqrtf(var + 1e-5f));
        }
        return;
    }
    int idx = bx - 1024;
    int yy = idx >> 6, xx = idx & 63;
    if (yy == 4) {
        if (xx == 0) {
            biasStack[t]       = bq[t] * 0.0625f;   // pow2: exact
            biasStack[t + 256] = bk[t];
            biasStack[t + 512] = bv[t];
        }
        return;
    }
    const float* s; u16* d; float sc = 1.f;
    if (yy == 0)      { s = Wq; d = Wqkv;          sc = 0.0625f; }
    else if (yy == 1) { s = Wk; d = Wqkv + 65536; }
    else if (yy == 2) { s = Wv; d = Wqkv + 131072; }
    else              { s = Wo; d = Woc; }
    int i = (xx * 256 + t) * 4;
    float4 f = *(const float4*)(s + i);
    u16 tmp[4] = {f2bf(f.x * sc), f2bf(f.y * sc), f2bf(f.z * sc), f2bf(f.w * sc)};
    *(uint2*)(d + i) = *(uint2*)tmp;
}

// ---------------- kernel 2: normalize + transpose -> xh [B*HW, C] bf16, fp32 in ------
__global__ __launch_bounds__(256) void ln_transpose_kernel(const float* __restrict__ x,
                                                           const float2* __restrict__ stats,
                                                           u16* __restrict__ xh) {
    __shared__ __align__(16) u16 tile[64 * 72];
    int b  = blockIdx.z;
    int c0 = blockIdx.y * 64;
    int p0 = blockIdx.x * 64;
    int t  = threadIdx.x;
    int c_loc = t >> 2;
    int pc    = (t & 3) * 16;
    int plane = b * CDIM + c0 + c_loc;
    float2 st = stats[plane];
    const float* px = x + (size_t)plane * HWDIM + p0 + pc;
#pragma unroll
    for (int j2 = 0; j2 < 4; j2++) {
        float4 v = *(const float4*)(px + j2 * 4);
        int p = pc + j2 * 4;
        tile[(p + 0) * 72 + c_loc] = f2bf((v.x - st.x) * st.y);
        tile[(p + 1) * 72 + c_loc] = f2bf((v.y - st.x) * st.y);
        tile[(p + 2) * 72 + c_loc] = f2bf((v.z - st.x) * st.y);
        tile[(p + 3) * 72 + c_loc] = f2bf((v.w - st.x) * st.y);
    }
    __syncthreads();
    int cc = (t & 7) * 8;
#pragma unroll
    for (int it = 0; it < 2; ++it) {
        int p_loc = (t >> 3) + it * 32;
        uint4 val = *(uint4*)&tile[p_loc * 72 + cc];
        *(uint4*)(xh + ((size_t)(b * HWDIM + p0 + p_loc)) * CDIM + c0 + cc) = val;
    }
}

// ---------------- kernel 3: QKV projection, 64m x 256n tiles ----------------
// grid (256, 3): by = weight group (q|k|v). A re-read 3x (24 MB) instead of 6x;
// B = one full 128 KB weight matrix per block, L2-resident (384 KB total).
__global__ __launch_bounds__(256) void gemm_qkv_kernel(const u16* __restrict__ xh,
                                                       const u16* __restrict__ Wqkv,
                                                       const float* __restrict__ biasStack,
                                                       u16* __restrict__ qkv) {
    __shared__ __align__(16) u16 lA[64 * 32];      // 4 KB
    __shared__ __align__(16) u16 lB[256 * 32];     // 16 KB
    int t = threadIdx.x, lane = t & 63, wid = t >> 6;
    int waveM = wid >> 1, waveN = wid & 1;         // wave: 32m x 128n
    int m0 = blockIdx.x * 64;
    int g  = blockIdx.y;                           // 0..2 = q|k|v
    const u16* Wg = Wqkv + g * 65536;
    f32x4 acc[2][8];
#pragma unroll
    for (int i = 0; i < 2; i++)
#pragma unroll
        for (int j = 0; j < 8; j++) acc[i][j] = (f32x4){0.f, 0.f, 0.f, 0.f};
    int fr = lane & 15, kq = (lane >> 4) * 8;
    int r = t >> 2, kc = (t & 3) * 8;
    const u16* gA = xh + (size_t)(m0 + r) * 256 + kc;
    const u16* gB = Wg + (size_t)r * 256 + kc;     // rows r, r+64, r+128, r+192
    u16* lA0 = lA + wid * 512;                     // wave-uniform; lane-contiguous 16B
    u16* lB0 = lB + wid * 512;
    for (int k0 = 0; k0 < 256; k0 += 32) {
        GLL16(gA + k0, lA0);
        GLL16(gB + k0,             lB0);
        GLL16(gB + k0 +  64 * 256, lB0 + 2048);
        GLL16(gB + k0 + 128 * 256, lB0 + 4096);
        GLL16(gB + k0 + 192 * 256, lB0 + 6144);
        __syncthreads();
        bf16x8 af[2], bfr[8];
#pragma unroll
        for (int i = 0; i < 2; i++)
            af[i]  = *(const bf16x8*)&lA[(waveM * 32 + i * 16 + fr) * 32 + kq];
#pragma unroll
        for (int j = 0; j < 8; j++)
            bfr[j] = *(const bf16x8*)&lB[(waveN * 128 + j * 16 + fr) * 32 + kq];
#pragma unroll
        for (int i = 0; i < 2; i++)
#pragma unroll
            for (int j = 0; j < 8; j++)
                acc[i][j] = __builtin_amdgcn_mfma_f32_16x16x32_bf16(af[i], bfr[j], acc[i][j], 0, 0, 0);
        __syncthreads();
    }
    int r0 = (lane >> 4) * 4;
#pragma unroll
    for (int j = 0; j < 8; j++) {
        int nl = waveN * 128 + j * 16 + fr;
        int ng = g * 256 + nl;                     // column in qkv row
        float bval = biasStack[ng];
#pragma unroll
        for (int i = 0; i < 2; i++) {
            int mrow = m0 + waveM * 32 + i * 16 + r0;
#pragma unroll
            for (int rr = 0; rr < 4; rr++)
                qkv[(size_t)(mrow + rr) * 768 + ng] = f2bf(acc[i][j][rr] + bval);
        }
    }
}

// ---------------- kernel 4: 3x3 window attention, 16 lanes/pixel, 4 pixels/wave ------
__global__ __launch_bounds__(256) void attn_kernel(const u16* __restrict__ qkv,
                                                   const float* __restrict__ biasStack,
                                                   u16* __restrict__ ctx) {
    int t = threadIdx.x, wid = t >> 6, lane = t & 63;
    int pl = lane >> 4, ln16 = lane & 15;
    int pix = blockIdx.x * 16 + wid * 4 + pl;
    int h = (pix >> 6) & 63, w = pix & 63;
    int ch = ln16 * 16;
    const u16* qrow = qkv + (size_t)pix * 768 + ch;
    float qv[16];
    unpack8(*(const uint4*)qrow,       qv);
    unpack8(*(const uint4*)(qrow + 8), qv + 8);
    float part[9];
    int off[9];
#pragma unroll
    for (int n = 0; n < 9; n++) {
        int dy = n / 3 - 1, dx = n % 3 - 1;
        int hh = h + dy, ww = w + dx;
        bool inb = ((unsigned)hh < 64u) && ((unsigned)ww < 64u);
        off[n] = inb ? ((pix + dy * 64 + dx) * 768) : -1;
        float kv[16];
        if (off[n] >= 0) {
            const u16* p = qkv + off[n] + 256 + ch;
            unpack8(*(const uint4*)p,       kv);
            unpack8(*(const uint4*)(p + 8), kv + 8);
        } else {
            const float* p = biasStack + 256 + ch;
#pragma unroll
            for (int c = 0; c < 4; c++) *(float4*)(kv + c * 4) = *(const float4*)(p + c * 4);
        }
        float d = 0.f;
#pragma unroll
        for (int c = 0; c < 16; c++) d += qv[c] * kv[c];
        part[n] = d;
    }
#pragma unroll
    for (int o = 8; o; o >>= 1) {
#pragma unroll
        for (int n = 0; n < 9; n++) part[n] += __shfl_xor(part[n], o);
    }
    float m = part[0];
#pragma unroll
    for (int n = 1; n < 9; n++) m = fmaxf(m, part[n]);
    float e[9], s = 0.f;
#pragma unroll
    for (int n = 0; n < 9; n++) { e[n] = __expf(part[n] - m); s += e[n]; }
    float inv = 1.f / s;
    float acc[16];
#pragma unroll
    for (int c = 0; c < 16; c++) acc[c] = 0.f;
#pragma unroll
    for (int n = 0; n < 9; n++) {
        float vv[16];
        if (off[n] >= 0) {
            const u16* p = qkv + off[n] + 512 + ch;
            unpack8(*(const uint4*)p,       vv);
            unpack8(*(const uint4*)(p + 8), vv + 8);
        } else {
            const float* p = biasStack + 512 + ch;
#pragma unroll
            for (int c = 0; c < 4; c++) *(float4*)(vv + c * 4) = *(const float4*)(p + c * 4);
        }
        float wn = e[n] * inv;
#pragma unroll
        for (int c = 0; c < 16; c++) acc[c] += wn * vv[c];
    }
    u32 wds[8];
#pragma unroll
    for (int c = 0; c < 8; c++)
        wds[c] = (u32)f2bf(acc[2 * c]) | ((u32)f2bf(acc[2 * c + 1]) << 16);
    u16* dst = ctx + (size_t)pix * 256 + ch;
    *(uint4*)dst       = make_uint4(wds[0], wds[1], wds[2], wds[3]);
    *(uint4*)(dst + 8) = make_uint4(wds[4], wds[5], wds[6], wds[7]);
}

// ---------------- kernel 5: output projection, 128x64 tile, BK=32 --------------------
__global__ __launch_bounds__(256) void gemm_out_kernel(const u16* __restrict__ ctx,
                                                       const u16* __restrict__ Wo,
                                                       const float* __restrict__ bo,
                                                       float* __restrict__ out) {
    __shared__ __align__(16) u16 lA[128 * 32];
    __shared__ __align__(16) u16 lB[64 * 32];
    int t = threadIdx.x, lane = t & 63, wid = t >> 6;
    int waveM = wid >> 1, waveN = wid & 1;
    int m0 = blockIdx.x * 128;
    int n0 = blockIdx.y * 64;
    f32x4 acc[4][2];
#pragma unroll
    for (int i = 0; i < 4; i++)
#pragma unroll
        for (int j = 0; j < 2; j++) acc[i][j] = (f32x4){0.f, 0.f, 0.f, 0.f};
    int fr = lane & 15, kq = (lane >> 4) * 8;
    int r = t >> 2, kc = (t & 3) * 8;
    const u16* gA0 = ctx + (size_t)(m0 + r) * 256 + kc;
    const u16* gA1 = gA0 + 64 * 256;
    const u16* gB0 = Wo + (size_t)(n0 + r) * 256 + kc;
    u16* lA0 = lA + wid * 512;
    u16* lA1 = lA0 + 2048;
    u16* lB0 = lB + wid * 512;
    for (int k0 = 0; k0 < 256; k0 += 32) {
        GLL16(gA0 + k0, lA0);
        GLL16(gA1 + k0, lA1);
        GLL16(gB0 + k0, lB0);
        __syncthreads();
        bf16x8 af[4], bfr[2];
#pragma unroll
        for (int i = 0; i < 4; i++) af[i]  = *(const bf16x8*)&lA[(waveM * 64 + i * 16 + fr) * 32 + kq];
#pragma unroll
        for (int j = 0; j < 2; j++) bfr[j] = *(const bf16x8*)&lB[(waveN * 32 + j * 16 + fr) * 32 + kq];
#pragma unroll
        for (int i = 0; i < 4; i++)
#pragma unroll
            for (int j = 0; j < 2; j++)
                acc[i][j] = __builtin_amdgcn_mfma_f32_16x16x32_bf16(af[i], bfr[j], acc[i][j], 0, 0, 0);
        __syncthreads();
    }
    int r0 = (lane >> 4) * 4;
#pragma unroll
    for (int j = 0; j < 2; j++) {
        int ng = n0 + waveN * 32 + j * 16 + fr;
        float bval = bo[ng];
#pragma unroll
        for (int i = 0; i < 4; i++) {
            int m = m0 + waveM * 64 + i * 16 + r0;
            int bidx = m >> 12;
            int p = m & 4095;
            float4 vv = make_float4(acc[i][j][0] + bval, acc[i][j][1] + bval,
                                    acc[i][j][2] + bval, acc[i][j][3] + bval);
            *(float4*)(out + ((size_t)(bidx * 256 + ng)) * HWDIM + p) = vv;
        }
    }
}

extern "C" void kernel_launch(void* const* d_in, const int* in_sizes, int n_in,
                              void* d_out, int out_size, void* d_ws, size_t ws_size,
                              hipStream_t stream) {
    const float* x  = (const float*)d_in[0];
    const float* Wq = (const float*)d_in[1];
    const float* bq = (const float*)d_in[2];
    const float* Wk = (const float*)d_in[3];
    const float* bk = (const float*)d_in[4];
    const float* Wv = (const float*)d_in[5];
    const float* bv = (const float*)d_in[6];
    const float* Wo = (const float*)d_in[7];
    const float* bo = (const float*)d_in[8];
    float* out = (float*)d_out;

    char* wsb = (char*)d_ws;
    const size_t MB = 1ull << 20;

    if (ws_size < 34 * MB) {   // ws measured 256 MiB; guard only
        hipLaunchKernelGGL(fill_kernel, dim3((out_size + 255) / 256), dim3(256), 0, stream,
                           out, out_size);
        return;
    }

    float2* stats     = (float2*)wsb;
    float*  biasStack = (float*)(wsb + 16 * 1024);
    u16* Wqkv = (u16*)(wsb + 64 * 1024);
    u16* Woc  = (u16*)(wsb + 448 * 1024);
    u16* xh   = (u16*)(wsb + 1 * MB);
    u16* qkv  = (u16*)(wsb + 9 * MB);
    u16* ctx  = xh;

    hipLaunchKernelGGL(prep_kernel, dim3(1344), dim3(256), 0, stream,
                       x, Wq, Wk, Wv, Wo, bq, bk, bv, Wqkv, Woc, biasStack, stats);
    hipLaunchKernelGGL(ln_transpose_kernel, dim3(64, 4, 4), dim3(256), 0, stream, x, stats, xh);
    hipLaunchKernelGGL(gemm_qkv_kernel,     dim3(256, 3),   dim3(256), 0, stream,
                       xh, Wqkv, biasStack, qkv);
    hipLaunchKernelGGL(attn_kernel,         dim3(1024),     dim3(256), 0, stream,
                       qkv, biasStack, ctx);
    hipLaunchKernelGGL(gemm_out_kernel,     dim3(128, 4),   dim3(256), 0, stream,
                       ctx, Woc, bo, out);
}

// Round 14
// 128.908 us; speedup vs baseline: 1.0143x; 1.0143x over previous
//
#include <hip/hip_runtime.h>

typedef unsigned short u16;
typedef unsigned int   u32;

typedef __attribute__((ext_vector_type(4))) float f32x4;
typedef __attribute__((ext_vector_type(8))) short bf16x8;

#define HWDIM 4096
#define CDIM  256

__device__ __forceinline__ float bf2f(u16 u) { return __uint_as_float(((u32)u) << 16); }
__device__ __forceinline__ u16 f2bf(float f) {
    u32 u = __float_as_uint(f);
    u32 r = (u + 0x7fffu + ((u >> 16) & 1u)) >> 16;   // RNE
    return (u16)r;
}
__device__ __forceinline__ void unpack8(uint4 r, float* f) {
    f[0] = __uint_as_float(r.x << 16); f[1] = __uint_as_float(r.x & 0xffff0000u);
    f[2] = __uint_as_float(r.y << 16); f[3] = __uint_as_float(r.y & 0xffff0000u);
    f[4] = __uint_as_float(r.z << 16); f[5] = __uint_as_float(r.z & 0xffff0000u);
    f[6] = __uint_as_float(r.w << 16); f[7] = __uint_as_float(r.w & 0xffff0000u);
}

// async global->LDS, 16 B per lane; lds dest = wave-uniform base + lane*16 (m104/m108)
#define GLL16(g, l) \
    __builtin_amdgcn_global_load_lds((const __attribute__((address_space(1))) u32*)(g), \
                                     (__attribute__((address_space(3))) u32*)(l), 16, 0, 0)

// ---------------- diagnostic fill (only if ws_size too small; ws measured 256 MiB) ----
__global__ __launch_bounds__(256) void fill_kernel(float* __restrict__ out, int n) {
    int i = blockIdx.x * 256 + threadIdx.x;
    if (i < n) out[i] = 1.0f;
}

// ---------------- kernel 0: fused prep = ln_stats (bx<1024) + weight/bias conv -------
__global__ __launch_bounds__(256) void prep_kernel(const float* __restrict__ x,
                                                   const float* __restrict__ Wq,
                                                   const float* __restrict__ Wk,
                                                   const float* __restrict__ Wv,
                                                   const float* __restrict__ Wo,
                                                   const float* __restrict__ bq,
                                                   const float* __restrict__ bk,
                                                   const float* __restrict__ bv,
                                                   u16* __restrict__ Wqkv,
                                                   u16* __restrict__ Woc,
                                                   float* __restrict__ biasStack,
                                                   float2* __restrict__ stats) {
    int bx = blockIdx.x;
    int t = threadIdx.x;
    if (bx < 1024) {
        const float* px = x + (size_t)bx * HWDIM;
        float sum = 0.f, ss = 0.f;
#pragma unroll
        for (int it = 0; it < 4; ++it) {
            float4 v = *(const float4*)(px + (t + it * 256) * 4);
            sum += v.x + v.y + v.z + v.w;
            ss  += v.x * v.x + v.y * v.y + v.z * v.z + v.w * v.w;
        }
#pragma unroll
        for (int o = 32; o; o >>= 1) { sum += __shfl_xor(sum, o); ss += __shfl_xor(ss, o); }
        __shared__ float s1[4], s2[4];
        int wid = t >> 6, lane = t & 63;
        if (lane == 0) { s1[wid] = sum; s2[wid] = ss; }
        __syncthreads();
        if (t == 0) {
            float S = s1[0] + s1[1] + s1[2] + s1[3];
            float Q = s2[0] + s2[1] + s2[2] + s2[3];
            float mu  = S * (1.f / HWDIM);
            float var = Q * (1.f / HWDIM) - mu * mu;
            stats[bx] = make_float2(mu, rsqrtf(var + 1e-5f));
        }
        return;
    }
    int idx = bx - 1024;
    int yy = idx >> 6, xx = idx & 63;
    if (yy == 4) {
        if (xx == 0) {
            biasStack[t]       = bq[t] * 0.0625f;   // pow2: exact
            biasStack[t + 256] = bk[t];
            biasStack[t + 512] = bv[t];
        }
        return;
    }
    const float* s; u16* d; float sc = 1.f;
    if (yy == 0)      { s = Wq; d = Wqkv;          sc = 0.0625f; }
    else if (yy == 1) { s = Wk; d = Wqkv + 65536; }
    else if (yy == 2) { s = Wv; d = Wqkv + 131072; }
    else              { s = Wo; d = Woc; }
    int i = (xx * 256 + t) * 4;
    float4 f = *(const float4*)(s + i);
    u16 tmp[4] = {f2bf(f.x * sc), f2bf(f.y * sc), f2bf(f.z * sc), f2bf(f.w * sc)};
    *(uint2*)(d + i) = *(uint2*)tmp;
}

// ---------------- kernel 3: QKV projection with fused layernorm A-staging ------------
// grid (256, 3): by = weight group (q|k|v). Each block normalizes its 64-pixel A-tile
// directly from fp32 x into LDS [64][264] bf16 (full K resident; no xh buffer).
// B = one full 128 KB weight matrix per block, staged in k-panels via GLL16.
#define ASTRIDE 264
__global__ __launch_bounds__(256) void gemm_qkv_kernel(const float* __restrict__ x,
                                                       const float2* __restrict__ stats,
                                                       const u16* __restrict__ Wqkv,
                                                       const float* __restrict__ biasStack,
                                                       u16* __restrict__ qkv) {
    __shared__ __align__(16) u16 lA[64 * ASTRIDE];   // 33 KB
    __shared__ __align__(16) u16 lB[256 * 32];       // 16 KB
    int t = threadIdx.x, lane = t & 63, wid = t >> 6;
    int waveM = wid >> 1, waveN = wid & 1;           // wave: 32m x 128n
    int m0 = blockIdx.x * 64;
    int g  = blockIdx.y;                             // 0..2 = q|k|v
    int b  = m0 >> 12, p0 = m0 & 4095;
    const u16* Wg = Wqkv + g * 65536;
    // ---- fused LN: thread t = channel t; 64 contiguous pixels ----
    float2 st = stats[b * 256 + t];
    const float* px = x + ((size_t)(b * 256 + t)) * HWDIM + p0;
#pragma unroll
    for (int jj = 0; jj < 16; jj++) {
        float4 v = *(const float4*)(px + jj * 4);
        int p = jj * 4;
        lA[(p + 0) * ASTRIDE + t] = f2bf((v.x - st.x) * st.y);
        lA[(p + 1) * ASTRIDE + t] = f2bf((v.y - st.x) * st.y);
        lA[(p + 2) * ASTRIDE + t] = f2bf((v.z - st.x) * st.y);
        lA[(p + 3) * ASTRIDE + t] = f2bf((v.w - st.x) * st.y);
    }
    f32x4 acc[2][8];
#pragma unroll
    for (int i = 0; i < 2; i++)
#pragma unroll
        for (int j = 0; j < 8; j++) acc[i][j] = (f32x4){0.f, 0.f, 0.f, 0.f};
    int fr = lane & 15, kq = (lane >> 4) * 8;
    int r = t >> 2, kc = (t & 3) * 8;
    const u16* gB = Wg + (size_t)r * 256 + kc;       // rows r, r+64, r+128, r+192
    u16* lB0 = lB + wid * 512;                       // wave-uniform; lane-contiguous 16B
    __syncthreads();                                 // lA ready
    for (int k0 = 0; k0 < 256; k0 += 32) {
        GLL16(gB + k0,             lB0);
        GLL16(gB + k0 +  64 * 256, lB0 + 2048);
        GLL16(gB + k0 + 128 * 256, lB0 + 4096);
        GLL16(gB + k0 + 192 * 256, lB0 + 6144);
        __syncthreads();                             // B panel ready
        bf16x8 af[2], bfr[8];
#pragma unroll
        for (int i = 0; i < 2; i++)
            af[i]  = *(const bf16x8*)&lA[(waveM * 32 + i * 16 + fr) * ASTRIDE + k0 + kq];
#pragma unroll
        for (int j = 0; j < 8; j++)
            bfr[j] = *(const bf16x8*)&lB[(waveN * 128 + j * 16 + fr) * 32 + kq];
#pragma unroll
        for (int i = 0; i < 2; i++)
#pragma unroll
            for (int j = 0; j < 8; j++)
                acc[i][j] = __builtin_amdgcn_mfma_f32_16x16x32_bf16(af[i], bfr[j], acc[i][j], 0, 0, 0);
        __syncthreads();                             // protect lB for next panel
    }
    int r0 = (lane >> 4) * 4;
#pragma unroll
    for (int j = 0; j < 8; j++) {
        int nl = waveN * 128 + j * 16 + fr;
        int ng = g * 256 + nl;                       // column in qkv row
        float bval = biasStack[ng];
#pragma unroll
        for (int i = 0; i < 2; i++) {
            int mrow = m0 + waveM * 32 + i * 16 + r0;
#pragma unroll
            for (int rr = 0; rr < 4; rr++)
                qkv[(size_t)(mrow + rr) * 768 + ng] = f2bf(acc[i][j][rr] + bval);
        }
    }
}

// ---------------- kernel 4: 3x3 window attention, 16 lanes/pixel, 4 pixels/wave ------
__global__ __launch_bounds__(256) void attn_kernel(const u16* __restrict__ qkv,
                                                   const float* __restrict__ biasStack,
                                                   u16* __restrict__ ctx) {
    int t = threadIdx.x, wid = t >> 6, lane = t & 63;
    int pl = lane >> 4, ln16 = lane & 15;
    int pix = blockIdx.x * 16 + wid * 4 + pl;
    int h = (pix >> 6) & 63, w = pix & 63;
    int ch = ln16 * 16;
    const u16* qrow = qkv + (size_t)pix * 768 + ch;
    float qv[16];
    unpack8(*(const uint4*)qrow,       qv);
    unpack8(*(const uint4*)(qrow + 8), qv + 8);
    float part[9];
    int off[9];
#pragma unroll
    for (int n = 0; n < 9; n++) {
        int dy = n / 3 - 1, dx = n % 3 - 1;
        int hh = h + dy, ww = w + dx;
        bool inb = ((unsigned)hh < 64u) && ((unsigned)ww < 64u);
        off[n] = inb ? ((pix + dy * 64 + dx) * 768) : -1;
        float kv[16];
        if (off[n] >= 0) {
            const u16* p = qkv + off[n] + 256 + ch;
            unpack8(*(const uint4*)p,       kv);
            unpack8(*(const uint4*)(p + 8), kv + 8);
        } else {
            const float* p = biasStack + 256 + ch;
#pragma unroll
            for (int c = 0; c < 4; c++) *(float4*)(kv + c * 4) = *(const float4*)(p + c * 4);
        }
        float d = 0.f;
#pragma unroll
        for (int c = 0; c < 16; c++) d += qv[c] * kv[c];
        part[n] = d;
    }
#pragma unroll
    for (int o = 8; o; o >>= 1) {
#pragma unroll
        for (int n = 0; n < 9; n++) part[n] += __shfl_xor(part[n], o);
    }
    float m = part[0];
#pragma unroll
    for (int n = 1; n < 9; n++) m = fmaxf(m, part[n]);
    float e[9], s = 0.f;
#pragma unroll
    for (int n = 0; n < 9; n++) { e[n] = __expf(part[n] - m); s += e[n]; }
    float inv = 1.f / s;
    float acc[16];
#pragma unroll
    for (int c = 0; c < 16; c++) acc[c] = 0.f;
#pragma unroll
    for (int n = 0; n < 9; n++) {
        float vv[16];
        if (off[n] >= 0) {
            const u16* p = qkv + off[n] + 512 + ch;
            unpack8(*(const uint4*)p,       vv);
            unpack8(*(const uint4*)(p + 8), vv + 8);
        } else {
            const float* p = biasStack + 512 + ch;
#pragma unroll
            for (int c = 0; c < 4; c++) *(float4*)(vv + c * 4) = *(const float4*)(p + c * 4);
        }
        float wn = e[n] * inv;
#pragma unroll
        for (int c = 0; c < 16; c++) acc[c] += wn * vv[c];
    }
    u32 wds[8];
#pragma unroll
    for (int c = 0; c < 8; c++)
        wds[c] = (u32)f2bf(acc[2 * c]) | ((u32)f2bf(acc[2 * c + 1]) << 16);
    u16* dst = ctx + (size_t)pix * 256 + ch;
    *(uint4*)dst       = make_uint4(wds[0], wds[1], wds[2], wds[3]);
    *(uint4*)(dst + 8) = make_uint4(wds[4], wds[5], wds[6], wds[7]);
}

// ---------------- kernel 5: output projection, 128x64 tile, BK=32 --------------------
__global__ __launch_bounds__(256) void gemm_out_kernel(const u16* __restrict__ ctx,
                                                       const u16* __restrict__ Wo,
                                                       const float* __restrict__ bo,
                                                       float* __restrict__ out) {
    __shared__ __align__(16) u16 lA[128 * 32];
    __shared__ __align__(16) u16 lB[64 * 32];
    int t = threadIdx.x, lane = t & 63, wid = t >> 6;
    int waveM = wid >> 1, waveN = wid & 1;
    int m0 = blockIdx.x * 128;
    int n0 = blockIdx.y * 64;
    f32x4 acc[4][2];
#pragma unroll
    for (int i = 0; i < 4; i++)
#pragma unroll
        for (int j = 0; j < 2; j++) acc[i][j] = (f32x4){0.f, 0.f, 0.f, 0.f};
    int fr = lane & 15, kq = (lane >> 4) * 8;
    int r = t >> 2, kc = (t & 3) * 8;
    const u16* gA0 = ctx + (size_t)(m0 + r) * 256 + kc;
    const u16* gA1 = gA0 + 64 * 256;
    const u16* gB0 = Wo + (size_t)(n0 + r) * 256 + kc;
    u16* lA0 = lA + wid * 512;
    u16* lA1 = lA0 + 2048;
    u16* lB0 = lB + wid * 512;
    for (int k0 = 0; k0 < 256; k0 += 32) {
        GLL16(gA0 + k0, lA0);
        GLL16(gA1 + k0, lA1);
        GLL16(gB0 + k0, lB0);
        __syncthreads();
        bf16x8 af[4], bfr[2];
#pragma unroll
        for (int i = 0; i < 4; i++) af[i]  = *(const bf16x8*)&lA[(waveM * 64 + i * 16 + fr) * 32 + kq];
#pragma unroll
        for (int j = 0; j < 2; j++) bfr[j] = *(const bf16x8*)&lB[(waveN * 32 + j * 16 + fr) * 32 + kq];
#pragma unroll
        for (int i = 0; i < 4; i++)
#pragma unroll
            for (int j = 0; j < 2; j++)
                acc[i][j] = __builtin_amdgcn_mfma_f32_16x16x32_bf16(af[i], bfr[j], acc[i][j], 0, 0, 0);
        __syncthreads();
    }
    int r0 = (lane >> 4) * 4;
#pragma unroll
    for (int j = 0; j < 2; j++) {
        int ng = n0 + waveN * 32 + j * 16 + fr;
        float bval = bo[ng];
#pragma unroll
        for (int i = 0; i < 4; i++) {
            int m = m0 + waveM * 64 + i * 16 + r0;
            int bidx = m >> 12;
            int p = m & 4095;
            float4 vv = make_float4(acc[i][j][0] + bval, acc[i][j][1] + bval,
                                    acc[i][j][2] + bval, acc[i][j][3] + bval);
            *(float4*)(out + ((size_t)(bidx * 256 + ng)) * HWDIM + p) = vv;
        }
    }
}

extern "C" void kernel_launch(void* const* d_in, const int* in_sizes, int n_in,
                              void* d_out, int out_size, void* d_ws, size_t ws_size,
                              hipStream_t stream) {
    const float* x  = (const float*)d_in[0];
    const float* Wq = (const float*)d_in[1];
    const float* bq = (const float*)d_in[2];
    const float* Wk = (const float*)d_in[3];
    const float* bk = (const float*)d_in[4];
    const float* Wv = (const float*)d_in[5];
    const float* bv = (const float*)d_in[6];
    const float* Wo = (const float*)d_in[7];
    const float* bo = (const float*)d_in[8];
    float* out = (float*)d_out;

    char* wsb = (char*)d_ws;
    const size_t MB = 1ull << 20;

    if (ws_size < 34 * MB) {   // ws measured 256 MiB; guard only
        hipLaunchKernelGGL(fill_kernel, dim3((out_size + 255) / 256), dim3(256), 0, stream,
                           out, out_size);
        return;
    }

    // workspace: stats 8KB @0 | biasStack 3KB @16KB | Wqkv 384KB @64KB | Woc 128KB @448KB
    //            ctx 8MB @1MB | qkv 24MB @9MB
    float2* stats     = (float2*)wsb;
    float*  biasStack = (float*)(wsb + 16 * 1024);
    u16* Wqkv = (u16*)(wsb + 64 * 1024);
    u16* Woc  = (u16*)(wsb + 448 * 1024);
    u16* ctx  = (u16*)(wsb + 1 * MB);
    u16* qkv  = (u16*)(wsb + 9 * MB);

    hipLaunchKernelGGL(prep_kernel, dim3(1344), dim3(256), 0, stream,
                       x, Wq, Wk, Wv, Wo, bq, bk, bv, Wqkv, Woc, biasStack, stats);
    hipLaunchKernelGGL(gemm_qkv_kernel, dim3(256, 3), dim3(256), 0, stream,
                       x, stats, Wqkv, biasStack, qkv);
    hipLaunchKernelGGL(attn_kernel,     dim3(1024),   dim3(256), 0, stream,
                       qkv, biasStack, ctx);
    hipLaunchKernelGGL(gemm_out_kernel, dim3(128, 4), dim3(256), 0, stream,
                       ctx, Woc, bo, out);
}